// Round 2
// baseline (582.501 us; speedup 1.0000x reference)
//
#include <hip/hip_runtime.h>
#include <hip/hip_bf16.h>
#include <math.h>

#define HEADS 8
#define CH    512
#define S     1024
#define NKV   320
#define DH    64
#define BATCH 32

typedef __attribute__((ext_vector_type(8))) short short8;
typedef __attribute__((ext_vector_type(4))) short short4v;
typedef __attribute__((ext_vector_type(4))) float float4v;
typedef __attribute__((ext_vector_type(4))) unsigned int uint4v;

__device__ __forceinline__ short f2bf(float f) {
    __hip_bfloat16 h = __float2bfloat16(f);
    return *reinterpret_cast<short*>(&h);
}

__device__ __forceinline__ float fexp2(float x) {
#if __has_builtin(__builtin_amdgcn_exp2f)
    return __builtin_amdgcn_exp2f(x);
#else
    return exp2f(x);
#endif
}

// async global->LDS DMA, 16B/lane. LDS base must be wave-uniform; HW adds lane*16.
#define GLOAD_LDS16(gp, lp) __builtin_amdgcn_global_load_lds( \
    (const __attribute__((address_space(1))) void*)(gp),      \
    (__attribute__((address_space(3))) void*)(lp), 16, 0, 0)

// ---------------------------------------------------------------------------
// Pool x: [B,C,32,32] -> xp [B,C,320] fp32 (mean-w | mean-h | 2x2 avg)
// ---------------------------------------------------------------------------
__global__ __launch_bounds__(256) void pool_kernel(const float* __restrict__ x,
                                                   float* __restrict__ xp) {
    __shared__ float sm[4][1024];
    const int w = threadIdx.x >> 6;
    const int l = threadIdx.x & 63;
    const int p = blockIdx.x * 4 + w;
    const float* src = x + (size_t)p * 1024;
    #pragma unroll
    for (int j = 0; j < 16; ++j) sm[w][j * 64 + l] = src[j * 64 + l];
    __syncthreads();
    float* dst = xp + (size_t)p * NKV;
    const float* pl = sm[w];
    #pragma unroll
    for (int g = 0; g < 5; ++g) {
        const int nn = g * 64 + l;
        float r;
        if (nn < 32) {
            const int h = nn; float s = 0.f;
            #pragma unroll
            for (int ww = 0; ww < 32; ++ww) s += pl[h * 32 + ww];
            r = s * (1.0f / 32.0f);
        } else if (nn < 64) {
            const int ww = nn - 32; float s = 0.f;
            #pragma unroll
            for (int h = 0; h < 32; ++h) s += pl[h * 32 + ww];
            r = s * (1.0f / 32.0f);
        } else {
            const int i = nn - 64;
            const int ph = i >> 4, pw = i & 15;
            r = 0.25f * (pl[(2 * ph) * 32 + 2 * pw]     + pl[(2 * ph) * 32 + 2 * pw + 1] +
                         pl[(2 * ph + 1) * 32 + 2 * pw] + pl[(2 * ph + 1) * 32 + 2 * pw + 1]);
        }
        dst[nn] = r;
    }
}

// ---------------------------------------------------------------------------
// Transpose-cast: in [bz][R][C] fp32 -> out [bz][C][R] bf16. grid (C/64, R/64, B)
// ---------------------------------------------------------------------------
__global__ __launch_bounds__(256) void tcast(const float* __restrict__ in,
                                             short* __restrict__ out, int R, int C) {
    __shared__ float sm[64][65];
    const int t = threadIdx.x;
    const int c0 = blockIdx.x * 64, r0 = blockIdx.y * 64;
    const float* ib = in + ((size_t)blockIdx.z * R + r0) * C + c0;
    #pragma unroll
    for (int rep = 0; rep < 4; ++rep) {
        const int r = rep * 16 + (t >> 4), c = (t & 15) * 4;
        const float4 v = *(const float4*)&ib[(size_t)r * C + c];
        sm[r][c] = v.x; sm[r][c + 1] = v.y; sm[r][c + 2] = v.z; sm[r][c + 3] = v.w;
    }
    __syncthreads();
    short* ob = out + ((size_t)blockIdx.z * C + c0) * R + r0;
    #pragma unroll
    for (int rep = 0; rep < 4; ++rep) {
        const int cr = rep * 16 + (t >> 4), rc = (t & 15) * 4;
        short4v p;
        #pragma unroll
        for (int e = 0; e < 4; ++e) p[e] = f2bf(sm[rc + e][cr]);
        *(short4v*)&ob[(size_t)cr * R + rc] = p;
    }
}

// ---------------------------------------------------------------------------
// Flat fp32 -> bf16 cast (weights). n divisible by 4.
// ---------------------------------------------------------------------------
__global__ __launch_bounds__(256) void castw(const float* __restrict__ in,
                                             short* __restrict__ out, int n) {
    const int i = (blockIdx.x * 256 + threadIdx.x) * 4;
    if (i < n) {
        const float4 v = *(const float4*)&in[i];
        short4v p = {f2bf(v.x), f2bf(v.y), f2bf(v.z), f2bf(v.w)};
        *(short4v*)&out[i] = p;
    }
}

// ---------------------------------------------------------------------------
// bf16 MFMA GEMM: Out[bz][row][col] = act( sum_k A[bz][row][k]*B[bz][col][k] )
// A [*,M,K], B [*,N,K] both K-contiguous bf16, K=512. 256 thr = 4 waves (2x2),
// wave tile (MT*16)x(NT*16), block tile BM=32*MT x BN=32*NT, BK=64.
// Staging via global_load_lds(16B) into XOR-swizzled packed LDS rows:
// physical chunk pc of row r holds logical chunk pc^(r&7) -> b128 frag reads
// are 2-way-conflict-free. ACT: 0 none(bf16), 1 sigmoid+0.125 on col<512(bf16),
// 2 +bias[row] (fp32 out), 3 *log2e (bf16, for exp2-softmax Q).
// ---------------------------------------------------------------------------
template <int MT, int NT, int ACT, typename OT>
__global__ __launch_bounds__(256) void gemm_bf16(const short* __restrict__ A, long sAb,
                                                 const short* __restrict__ B, long sBb,
                                                 const float* __restrict__ bias,
                                                 OT* __restrict__ C, int M, int N) {
    constexpr int K  = 512;
    constexpr int BM = 32 * MT, BN = 32 * NT;
    __shared__ short As[BM * 64];
    __shared__ short Bs[BN * 64];
    const int t = threadIdx.x, w = t >> 6, l = t & 63;
    const int wm = w >> 1, wn = w & 1, quad = l >> 4, m15 = l & 15;
    const int bz = blockIdx.z;
    const int n0 = blockIdx.x * BN, m0 = blockIdx.y * BM;
    const short* gA = A + (size_t)sAb * bz + (size_t)m0 * K;
    const short* gB = B + (size_t)sBb * bz + (size_t)n0 * K;
    const int lrow = l >> 3;     // row within an 8-row staging group
    const int pc   = l & 7;      // physical 16B chunk within row

    const float4v zf = {0.f, 0.f, 0.f, 0.f};
    float4v acc[MT][NT];
    #pragma unroll
    for (int i = 0; i < MT; ++i)
        #pragma unroll
        for (int j = 0; j < NT; ++j) acc[i][j] = zf;

    for (int k0 = 0; k0 < K; k0 += 64) {
        #pragma unroll
        for (int ii = w; ii < BM / 8; ii += 4) {
            const int row = ii * 8 + lrow;
            const int x = pc ^ (row & 7);
            GLOAD_LDS16(gA + (size_t)row * K + k0 + x * 8, &As[ii * 512]);
        }
        #pragma unroll
        for (int ii = w; ii < BN / 8; ii += 4) {
            const int row = ii * 8 + lrow;
            const int x = pc ^ (row & 7);
            GLOAD_LDS16(gB + (size_t)row * K + k0 + x * 8, &Bs[ii * 512]);
        }
        __syncthreads();
        #pragma unroll
        for (int ks = 0; ks < 2; ++ks) {
            const int xa = (((ks * 4 + quad) ^ (m15 & 7))) * 8;
            short8 aF[MT], bF[NT];
            #pragma unroll
            for (int i = 0; i < MT; ++i)
                aF[i] = *(const short8*)&As[((wm * MT + i) * 16 + m15) * 64 + xa];
            #pragma unroll
            for (int j = 0; j < NT; ++j)
                bF[j] = *(const short8*)&Bs[((wn * NT + j) * 16 + m15) * 64 + xa];
            #pragma unroll
            for (int i = 0; i < MT; ++i)
                #pragma unroll
                for (int j = 0; j < NT; ++j)
                    acc[i][j] = __builtin_amdgcn_mfma_f32_16x16x32_bf16(aF[i], bF[j], acc[i][j], 0, 0, 0);
        }
        __syncthreads();
    }

    OT* gC = C + (size_t)bz * M * N;
    #pragma unroll
    for (int i = 0; i < MT; ++i) {
        #pragma unroll
        for (int r = 0; r < 4; ++r) {
            const int row = m0 + (wm * MT + i) * 16 + quad * 4 + r;
            float bv = 0.f;
            if (ACT == 2) bv = bias[row];
            #pragma unroll
            for (int j = 0; j < NT; ++j) {
                const int col = n0 + (wn * NT + j) * 16 + m15;
                float v = acc[i][j][r];
                if (ACT == 1) { v = 1.0f / (1.0f + __expf(-v)); if (col < 512) v *= 0.125f; }
                if (ACT == 2) v += bv;
                if (ACT == 3) v *= 1.4426950408889634f;
                if constexpr (sizeof(OT) == 2)
                    ((short*)gC)[(size_t)row * N + col] = f2bf(v);
                else
                    ((float*)gC)[(size_t)row * N + col] = v;
            }
        }
    }
}

// ---------------------------------------------------------------------------
// MFMA attention, v3: merged s-tiles. One block = one (b, h, s-half of 512
// rows); 8 waves x 4 s-tile iterations of 128 rows. K and V live in SEPARATE
// LDS buffers (40960 B each, 81920 total -> exactly 2 blocks/CU), so the
// whole kernel has ONE barrier: {V global->reg (issued first, hides under K
// DMA), K global_load_lds sigma-permuted, V reg->LDS scatter} -> barrier ->
// 4 barrier-free iterations {Q prefetch, QK^T, softmax, PV, store}.
//
// sigma-permuted K staging (as v2): lane (quad,m15) gets acc[tt][r] =
// S[s=m15][n(tt,quad,r)] such that PV A-frags are the lane's own packed P
// dwords -> zero cross-lane P traffic. No row-max (logits bounded, softmax
// shift-invariant); Q pre-scaled by log2e (gemm ACT=3) -> p = exp2(fma(pos,
// log2e, a)) is a single fma + v_exp.
// ---------------------------------------------------------------------------
__global__ __launch_bounds__(512, 4) void attn_mfma(const short* __restrict__ qT,
                                                    const short* __restrict__ kvT,
                                                    const float* __restrict__ pos,
                                                    short* __restrict__ aoT) {
    __shared__ short smK[8 * 320 * 8];   // 40960 B: K packed [dg][n][8]
    __shared__ short smV[64 * 320];      // 40960 B: V^T [d][chunk x^(d&7)][8]
    const int tid = threadIdx.x, w = tid >> 6, l = tid & 63;
    const int quad = l >> 4, m15 = l & 15;
    const int b = blockIdx.z, h = blockIdx.y, s0 = blockIdx.x * 512;
    const short* kvb = kvT + (size_t)b * NKV * 1024;
    constexpr float LOG2E = 1.4426950408889634f;

    // ---- V-half global->reg, issued FIRST (returns while K DMA flies) ----
    short8 vreg[5];
    #pragma unroll
    for (int it = 0; it < 5; ++it) {
        const int i2 = it * 512 + tid;
        const int n5 = i2 & 31, d8 = (i2 >> 5) & 7, nb = i2 >> 8;
        const int n = nb * 32 + n5;
        vreg[it] = *(const short8*)&kvb[(size_t)n * 1024 + 512 + h * 64 + d8 * 8];
    }
    // ---- stage K, sigma-permuted rows: n_off = 32*l5+16*l3+8*l2+4*l4+2*l1+l0
    const int nperm = (l & 35) | ((l & 12) << 1) | ((l & 16) >> 2);
    #pragma unroll
    for (int i2 = w; i2 < 40; i2 += 8) {
        const int nb = i2 % 5, dg = i2 / 5;
        GLOAD_LDS16(kvb + (size_t)(nb * 64 + nperm) * 1024 + h * 64 + dg * 8,
                    &smK[(dg * 320 + nb * 64) * 8]);
    }
    // ---- scatter V^T into smV: chunk x of row d stored at x^(d&7) ----
    #pragma unroll
    for (int it = 0; it < 5; ++it) {
        const int i2 = it * 512 + tid;
        const int n5 = i2 & 31, d8 = (i2 >> 5) & 7, nb = i2 >> 8;
        const int n = nb * 32 + n5;
        const int x = n >> 3;
        #pragma unroll
        for (int e = 0; e < 8; ++e)
            smV[(d8 * 8 + e) * 320 + ((x ^ e) * 8) + (n & 7)] = vreg[it][e];
    }

    // ---- Q frags for si=0 (global, no barrier needed) ----
    const short* qbase = qT + (size_t)(b * S + s0 + w * 16 + m15) * 512 + h * 64;
    short8 cq0 = *(const short8*)&qbase[quad * 8];
    short8 cq1 = *(const short8*)&qbase[32 + quad * 8];

    __syncthreads();   // the ONLY barrier: K DMA + V scatter complete

    const float4v zf = {0.f, 0.f, 0.f, 0.f};
    #pragma unroll 1
    for (int si = 0; si < 4; ++si) {
        // prefetch next iteration's Q
        short8 nq0, nq1;
        if (si < 3) {
            const short* nqb = qbase + (size_t)(si + 1) * 128 * 512;
            nq0 = *(const short8*)&nqb[quad * 8];
            nq1 = *(const short8*)&nqb[32 + quad * 8];
        }

        // ---- QK^T + pos + exp2 + pack, tile by tile ----
        const float* posrow = pos + (size_t)(s0 + si * 128 + w * 16 + m15) * NKV + quad * 8;
        unsigned int P[40];
        float lpart = 0.f;
        #pragma unroll
        for (int tt = 0; tt < 20; ++tt) {
            float4v a = zf;
            const short8 k0 = *(const short8*)&smK[(quad * 320 + tt * 16 + m15) * 8];
            const short8 k1 = *(const short8*)&smK[((4 + quad) * 320 + tt * 16 + m15) * 8];
            a = __builtin_amdgcn_mfma_f32_16x16x32_bf16(k0, cq0, a, 0, 0, 0);
            a = __builtin_amdgcn_mfma_f32_16x16x32_bf16(k1, cq1, a, 0, 0, 0);
            const int n0 = (tt >> 2) * 64 + ((tt >> 1) & 1) * 32 + (tt & 1) * 4;
            const float4 pv = *(const float4*)&posrow[n0];
            const float p0 = fexp2(fmaf(pv.x, LOG2E, a[0]));
            const float p1 = fexp2(fmaf(pv.y, LOG2E, a[1]));
            const float p2 = fexp2(fmaf(pv.z, LOG2E, a[2]));
            const float p3 = fexp2(fmaf(pv.w, LOG2E, a[3]));
            lpart += (p0 + p1) + (p2 + p3);
            P[tt * 2]     = (unsigned int)(unsigned short)f2bf(p0) |
                            ((unsigned int)(unsigned short)f2bf(p1) << 16);
            P[tt * 2 + 1] = (unsigned int)(unsigned short)f2bf(p2) |
                            ((unsigned int)(unsigned short)f2bf(p3) << 16);
        }

        // ---- row sum across quads (each quad holds a disjoint n-subset) ----
        float lrow = lpart;
        lrow += __shfl_xor(lrow, 16, 64);
        lrow += __shfl_xor(lrow, 32, 64);
        const float invl = 1.0f / lrow;
        float inv[4];
        #pragma unroll
        for (int r = 0; r < 4; ++r)
            inv[r] = __shfl(invl, (l & 48) | (quad * 4 + r), 64);

        // ---- P@V: A-frags direct from packed P regs; V^T B-frags from smV ----
        #pragma unroll
        for (int half = 0; half < 2; ++half) {
            float4v O0 = zf, O1 = zf;
            #pragma unroll
            for (int c = 0; c < 5; ++c) {
                const uint4v u0 = {P[c * 8 + 0], P[c * 8 + 1], P[c * 8 + 2], P[c * 8 + 3]};
                const uint4v u1 = {P[c * 8 + 4], P[c * 8 + 5], P[c * 8 + 6], P[c * 8 + 7]};
                const short8 aP0 = __builtin_bit_cast(short8, u0);
                const short8 aP1 = __builtin_bit_cast(short8, u1);
                #pragma unroll
                for (int ks = 0; ks < 2; ++ks) {
                    const int xr = (c * 8 + ks * 4 + quad) ^ (m15 & 7);
                    const int dt0 = half * 2;
                    const short8 bV0 = *(const short8*)&smV[(dt0 * 16 + m15) * 320 + xr * 8];
                    const short8 bV1 = *(const short8*)&smV[((dt0 + 1) * 16 + m15) * 320 + xr * 8];
                    if (ks == 0) {
                        O0 = __builtin_amdgcn_mfma_f32_16x16x32_bf16(aP0, bV0, O0, 0, 0, 0);
                        O1 = __builtin_amdgcn_mfma_f32_16x16x32_bf16(aP0, bV1, O1, 0, 0, 0);
                    } else {
                        O0 = __builtin_amdgcn_mfma_f32_16x16x32_bf16(aP1, bV0, O0, 0, 0, 0);
                        O1 = __builtin_amdgcn_mfma_f32_16x16x32_bf16(aP1, bV1, O1, 0, 0, 0);
                    }
                }
            }
            // ---- normalize + direct bf16 output aoT[b][s][c] ----
            #pragma unroll
            for (int r = 0; r < 4; ++r) {
                const int s = s0 + si * 128 + w * 16 + quad * 4 + r;
                short* orow = &aoT[(size_t)(b * S + s) * 512 + h * 64 + (half * 2) * 16 + m15];
                orow[0]  = f2bf(O0[r] * inv[r]);
                orow[16] = f2bf(O1[r] * inv[r]);
            }
        }

        if (si < 3) { cq0 = nq0; cq1 = nq1; }
    }
}

// ---------------------------------------------------------------------------
extern "C" void kernel_launch(void* const* d_in, const int* in_sizes, int n_in,
                              void* d_out, int out_size, void* d_ws, size_t ws_size,
                              hipStream_t stream) {
    const float* x    = (const float*)d_in[0];
    const float* Wqkv = (const float*)d_in[1];
    const float* Wout = (const float*)d_in[2];
    const float* bout = (const float*)d_in[3];
    const float* pos  = (const float*)d_in[4];
    char* ws = (char*)d_ws;
    float* xp   = (float*)(ws + 0);            // [32][512][320] f32   20971520 B
    short* xT   = (short*)(ws + 20971520);     // [32][1024][512] bf16 33554432 B
    short* xpT  = (short*)(ws + 54525952);     // [32][320][512] bf16  10485760 B
    short* qT   = (short*)(ws + 65011712);     // [32][1024][512] bf16 33554432 B
    short* kvT  = (short*)(ws + 98566144);     // [32][320][1024] bf16 20971520 B
    short* aoT  = (short*)(ws + 119537664);    // [32][1024][512] bf16 33554432 B
    short* Wbf  = (short*)(ws + 153092096);    // [1536][512] bf16      1572864 B
    short* Wobf = (short*)(ws + 154664960);    // [512][512] bf16        524288 B
    float* out  = (float*)d_out;

    castw<<<dim3(768), 256, 0, stream>>>(Wqkv, Wbf, 1536 * 512);
    castw<<<dim3(256), 256, 0, stream>>>(Wout, Wobf, 512 * 512);
    pool_kernel<<<dim3(BATCH * CH / 4), 256, 0, stream>>>(x, xp);
    tcast<<<dim3(16, 8, BATCH), 256, 0, stream>>>(x, xT, CH, S);       // -> xT [s][c]
    tcast<<<dim3(5, 8, BATCH), 256, 0, stream>>>(xp, xpT, CH, NKV);    // -> xpT [n][c]
    // qT[b][s][c] = (xT . Wq) * log2e   (exp2-softmax pre-scale)
    gemm_bf16<4, 4, 3, short><<<dim3(4, 8, BATCH), 256, 0, stream>>>(
        xT, (long)S * CH, Wbf, 0, nullptr, qT, S, CH);
    // kvT[b][n][ckv] = sigmoid(xpT . Wkv), k-cols pre-scaled 0.125
    gemm_bf16<2, 8, 1, short><<<dim3(4, 5, BATCH), 256, 0, stream>>>(
        xpT, (long)NKV * CH, Wbf + CH * CH, 0, nullptr, kvT, NKV, 2 * CH);
    attn_mfma<<<dim3(2, HEADS, BATCH), 512, 0, stream>>>(qT, kvT, pos, aoT);
    // out[b][c][s] = Wout . aoT + bout  (fp32, direct coalesced)
    gemm_bf16<4, 4, 2, float><<<dim3(8, 4, BATCH), 256, 0, stream>>>(
        Wobf, 0, aoT, (long)S * CH, bout, out, CH, S);
}

// Round 3
// 546.865 us; speedup vs baseline: 1.0652x; 1.0652x over previous
//
#include <hip/hip_runtime.h>
#include <hip/hip_bf16.h>
#include <math.h>

#define HEADS 8
#define CH    512
#define S     1024
#define NKV   320
#define DH    64
#define BATCH 32

typedef __attribute__((ext_vector_type(8))) short short8;
typedef __attribute__((ext_vector_type(4))) short short4v;
typedef __attribute__((ext_vector_type(4))) float float4v;
typedef __attribute__((ext_vector_type(4))) unsigned int uint4v;

__device__ __forceinline__ short f2bf(float f) {
    __hip_bfloat16 h = __float2bfloat16(f);
    return *reinterpret_cast<short*>(&h);
}

__device__ __forceinline__ float fexp2(float x) {
#if __has_builtin(__builtin_amdgcn_exp2f)
    return __builtin_amdgcn_exp2f(x);
#else
    return exp2f(x);
#endif
}

// async global->LDS DMA, 16B/lane. LDS base must be wave-uniform; HW adds lane*16.
#define GLOAD_LDS16(gp, lp) __builtin_amdgcn_global_load_lds( \
    (const __attribute__((address_space(1))) void*)(gp),      \
    (__attribute__((address_space(3))) void*)(lp), 16, 0, 0)

// ---------------------------------------------------------------------------
// Pool x: [B,C,32,32] -> xp [B,C,320] fp32 (mean-w | mean-h | 2x2 avg)
// ---------------------------------------------------------------------------
__global__ __launch_bounds__(256) void pool_kernel(const float* __restrict__ x,
                                                   float* __restrict__ xp) {
    __shared__ float sm[4][1024];
    const int w = threadIdx.x >> 6;
    const int l = threadIdx.x & 63;
    const int p = blockIdx.x * 4 + w;
    const float* src = x + (size_t)p * 1024;
    #pragma unroll
    for (int j = 0; j < 16; ++j) sm[w][j * 64 + l] = src[j * 64 + l];
    __syncthreads();
    float* dst = xp + (size_t)p * NKV;
    const float* pl = sm[w];
    #pragma unroll
    for (int g = 0; g < 5; ++g) {
        const int nn = g * 64 + l;
        float r;
        if (nn < 32) {
            const int h = nn; float s = 0.f;
            #pragma unroll
            for (int ww = 0; ww < 32; ++ww) s += pl[h * 32 + ww];
            r = s * (1.0f / 32.0f);
        } else if (nn < 64) {
            const int ww = nn - 32; float s = 0.f;
            #pragma unroll
            for (int h = 0; h < 32; ++h) s += pl[h * 32 + ww];
            r = s * (1.0f / 32.0f);
        } else {
            const int i = nn - 64;
            const int ph = i >> 4, pw = i & 15;
            r = 0.25f * (pl[(2 * ph) * 32 + 2 * pw]     + pl[(2 * ph) * 32 + 2 * pw + 1] +
                         pl[(2 * ph + 1) * 32 + 2 * pw] + pl[(2 * ph + 1) * 32 + 2 * pw + 1]);
        }
        dst[nn] = r;
    }
}

// ---------------------------------------------------------------------------
// Transpose-cast: in [bz][R][C] fp32 -> out [bz][C][R] bf16. grid (C/64, R/64, B)
// ---------------------------------------------------------------------------
__global__ __launch_bounds__(256) void tcast(const float* __restrict__ in,
                                             short* __restrict__ out, int R, int C) {
    __shared__ float sm[64][65];
    const int t = threadIdx.x;
    const int c0 = blockIdx.x * 64, r0 = blockIdx.y * 64;
    const float* ib = in + ((size_t)blockIdx.z * R + r0) * C + c0;
    #pragma unroll
    for (int rep = 0; rep < 4; ++rep) {
        const int r = rep * 16 + (t >> 4), c = (t & 15) * 4;
        const float4 v = *(const float4*)&ib[(size_t)r * C + c];
        sm[r][c] = v.x; sm[r][c + 1] = v.y; sm[r][c + 2] = v.z; sm[r][c + 3] = v.w;
    }
    __syncthreads();
    short* ob = out + ((size_t)blockIdx.z * C + c0) * R + r0;
    #pragma unroll
    for (int rep = 0; rep < 4; ++rep) {
        const int cr = rep * 16 + (t >> 4), rc = (t & 15) * 4;
        short4v p;
        #pragma unroll
        for (int e = 0; e < 4; ++e) p[e] = f2bf(sm[rc + e][cr]);
        *(short4v*)&ob[(size_t)cr * R + rc] = p;
    }
}

// ---------------------------------------------------------------------------
// Flat fp32 -> bf16 cast (weights). n divisible by 4.
// ---------------------------------------------------------------------------
__global__ __launch_bounds__(256) void castw(const float* __restrict__ in,
                                             short* __restrict__ out, int n) {
    const int i = (blockIdx.x * 256 + threadIdx.x) * 4;
    if (i < n) {
        const float4 v = *(const float4*)&in[i];
        short4v p = {f2bf(v.x), f2bf(v.y), f2bf(v.z), f2bf(v.w)};
        *(short4v*)&out[i] = p;
    }
}

// ---------------------------------------------------------------------------
// bf16 MFMA GEMM: Out[bz][row][col] = act( sum_k A[bz][row][k]*B[bz][col][k] )
// A [*,M,K], B [*,N,K] both K-contiguous bf16, K=512. 256 thr = 4 waves (2x2),
// wave tile (MT*16)x(NT*16), block tile BM=32*MT x BN=32*NT, BK=64.
// Staging via global_load_lds(16B) into XOR-swizzled packed LDS rows:
// physical chunk pc of row r holds logical chunk pc^(r&7) -> b128 frag reads
// are 2-way-conflict-free. ACT: 0 none(bf16), 1 sigmoid+0.125 on col<512(bf16),
// 2 +bias[row] (fp32 out), 3 *log2e (bf16, for exp2-softmax Q).
// ---------------------------------------------------------------------------
template <int MT, int NT, int ACT, typename OT>
__global__ __launch_bounds__(256) void gemm_bf16(const short* __restrict__ A, long sAb,
                                                 const short* __restrict__ B, long sBb,
                                                 const float* __restrict__ bias,
                                                 OT* __restrict__ C, int M, int N) {
    constexpr int K  = 512;
    constexpr int BM = 32 * MT, BN = 32 * NT;
    __shared__ short As[BM * 64];
    __shared__ short Bs[BN * 64];
    const int t = threadIdx.x, w = t >> 6, l = t & 63;
    const int wm = w >> 1, wn = w & 1, quad = l >> 4, m15 = l & 15;
    const int bz = blockIdx.z;
    const int n0 = blockIdx.x * BN, m0 = blockIdx.y * BM;
    const short* gA = A + (size_t)sAb * bz + (size_t)m0 * K;
    const short* gB = B + (size_t)sBb * bz + (size_t)n0 * K;
    const int lrow = l >> 3;     // row within an 8-row staging group
    const int pc   = l & 7;      // physical 16B chunk within row

    const float4v zf = {0.f, 0.f, 0.f, 0.f};
    float4v acc[MT][NT];
    #pragma unroll
    for (int i = 0; i < MT; ++i)
        #pragma unroll
        for (int j = 0; j < NT; ++j) acc[i][j] = zf;

    for (int k0 = 0; k0 < K; k0 += 64) {
        #pragma unroll
        for (int ii = w; ii < BM / 8; ii += 4) {
            const int row = ii * 8 + lrow;
            const int x = pc ^ (row & 7);
            GLOAD_LDS16(gA + (size_t)row * K + k0 + x * 8, &As[ii * 512]);
        }
        #pragma unroll
        for (int ii = w; ii < BN / 8; ii += 4) {
            const int row = ii * 8 + lrow;
            const int x = pc ^ (row & 7);
            GLOAD_LDS16(gB + (size_t)row * K + k0 + x * 8, &Bs[ii * 512]);
        }
        __syncthreads();
        #pragma unroll
        for (int ks = 0; ks < 2; ++ks) {
            const int xa = (((ks * 4 + quad) ^ (m15 & 7))) * 8;
            short8 aF[MT], bF[NT];
            #pragma unroll
            for (int i = 0; i < MT; ++i)
                aF[i] = *(const short8*)&As[((wm * MT + i) * 16 + m15) * 64 + xa];
            #pragma unroll
            for (int j = 0; j < NT; ++j)
                bF[j] = *(const short8*)&Bs[((wn * NT + j) * 16 + m15) * 64 + xa];
            #pragma unroll
            for (int i = 0; i < MT; ++i)
                #pragma unroll
                for (int j = 0; j < NT; ++j)
                    acc[i][j] = __builtin_amdgcn_mfma_f32_16x16x32_bf16(aF[i], bF[j], acc[i][j], 0, 0, 0);
        }
        __syncthreads();
    }

    OT* gC = C + (size_t)bz * M * N;
    #pragma unroll
    for (int i = 0; i < MT; ++i) {
        #pragma unroll
        for (int r = 0; r < 4; ++r) {
            const int row = m0 + (wm * MT + i) * 16 + quad * 4 + r;
            float bv = 0.f;
            if (ACT == 2) bv = bias[row];
            #pragma unroll
            for (int j = 0; j < NT; ++j) {
                const int col = n0 + (wn * NT + j) * 16 + m15;
                float v = acc[i][j][r];
                if (ACT == 1) { v = 1.0f / (1.0f + __expf(-v)); if (col < 512) v *= 0.125f; }
                if (ACT == 2) v += bv;
                if (ACT == 3) v *= 1.4426950408889634f;
                if constexpr (sizeof(OT) == 2)
                    ((short*)gC)[(size_t)row * N + col] = f2bf(v);
                else
                    ((float*)gC)[(size_t)row * N + col] = v;
            }
        }
    }
}

// ---------------------------------------------------------------------------
// MFMA attention, v4: merged s-tiles (v3 structure) with FUSED chunk loop to
// kill the v3 register spill. One block = one (b, h, 512 s-rows); 8 waves x 4
// s-tile iterations. K and V in separate LDS buffers (40960 B each -> exactly
// 2 blocks/CU); ONE barrier in the whole kernel.
//
// Fused inner loop: per 64-column chunk c, compute 4 score tiles (8 MFMA),
// exp2+pack into 8 TRANSIENT Pc dwords, immediately run the chunk's 8 PV
// MFMAs into persistent O[4] accumulators (unnormalized; inv applied at the
// store — softmax normalization is linear). Peak live regs ~80 (< 128 cap of
// launch_bounds(512,4)) vs v3's 40-reg P array + prefetch that spilled to
// scratch (FETCH 612 MB -> expect ~90 MB).
//
// sigma-permuted K staging: lane (quad,m15) gets score[s=m15][n(tt,quad,r)]
// such that PV A-frags are the lane's own packed Pc dwords -> zero cross-lane
// P traffic. No row-max (logits bounded, softmax shift-invariant); Q
// pre-scaled by log2e (gemm ACT=3) -> p = exp2(fma(pos, log2e, a)).
// ---------------------------------------------------------------------------
__global__ __launch_bounds__(512, 4) void attn_mfma(const short* __restrict__ qT,
                                                    const short* __restrict__ kvT,
                                                    const float* __restrict__ pos,
                                                    short* __restrict__ aoT) {
    __shared__ short smK[8 * 320 * 8];   // 40960 B: K packed [dg][n][8]
    __shared__ short smV[64 * 320];      // 40960 B: V^T [d][chunk x^(d&7)][8]
    const int tid = threadIdx.x, w = tid >> 6, l = tid & 63;
    const int quad = l >> 4, m15 = l & 15;
    const int b = blockIdx.z, h = blockIdx.y, s0 = blockIdx.x * 512;
    const short* kvb = kvT + (size_t)b * NKV * 1024;
    constexpr float LOG2E = 1.4426950408889634f;

    // ---- stage K, sigma-permuted rows: n_off = 32*l5+16*l3+8*l2+4*l4+2*l1+l0
    const int nperm = (l & 35) | ((l & 12) << 1) | ((l & 16) >> 2);
    #pragma unroll
    for (int i2 = w; i2 < 40; i2 += 8) {
        const int nb = i2 % 5, dg = i2 / 5;
        GLOAD_LDS16(kvb + (size_t)(nb * 64 + nperm) * 1024 + h * 64 + dg * 8,
                    &smK[(dg * 320 + nb * 64) * 8]);
    }
    // ---- V-half global->reg->LDS scatter (overlaps the K DMA in flight) ----
    // chunk x of V^T row d stored at x^(d&7)
    #pragma unroll
    for (int it = 0; it < 5; ++it) {
        const int i2 = it * 512 + tid;
        const int n5 = i2 & 31, d8 = (i2 >> 5) & 7, nb = i2 >> 8;
        const int n = nb * 32 + n5;
        const short8 v = *(const short8*)&kvb[(size_t)n * 1024 + 512 + h * 64 + d8 * 8];
        const int x = n >> 3;
        #pragma unroll
        for (int e = 0; e < 8; ++e)
            smV[(d8 * 8 + e) * 320 + ((x ^ e) * 8) + (n & 7)] = v[e];
    }

    __syncthreads();   // the ONLY barrier: K DMA + V scatter complete

    const short* qbase = qT + (size_t)(b * S + s0 + w * 16 + m15) * 512 + h * 64;
    const float4v zf = {0.f, 0.f, 0.f, 0.f};

    #pragma unroll 1
    for (int si = 0; si < 4; ++si) {
        const short* qb = qbase + (size_t)si * 128 * 512;
        const short8 cq0 = *(const short8*)&qb[quad * 8];
        const short8 cq1 = *(const short8*)&qb[32 + quad * 8];
        const float* posrow = pos + (size_t)(s0 + si * 128 + w * 16 + m15) * NKV + quad * 8;

        float4v O0 = zf, O1 = zf, O2 = zf, O3 = zf;
        float lpart = 0.f;

        #pragma unroll
        for (int c = 0; c < 5; ++c) {
            unsigned int Pc[8];
            // ---- 4 score tiles of this 64-col chunk: QK^T + pos + exp2 + pack
            #pragma unroll
            for (int t4 = 0; t4 < 4; ++t4) {
                const int tt = c * 4 + t4;
                float4v a = zf;
                const short8 k0 = *(const short8*)&smK[(quad * 320 + tt * 16 + m15) * 8];
                const short8 k1 = *(const short8*)&smK[((4 + quad) * 320 + tt * 16 + m15) * 8];
                a = __builtin_amdgcn_mfma_f32_16x16x32_bf16(k0, cq0, a, 0, 0, 0);
                a = __builtin_amdgcn_mfma_f32_16x16x32_bf16(k1, cq1, a, 0, 0, 0);
                const int n0 = c * 64 + (t4 >> 1) * 32 + (t4 & 1) * 4;
                const float4 pv = *(const float4*)&posrow[n0];
                const float p0 = fexp2(fmaf(pv.x, LOG2E, a[0]));
                const float p1 = fexp2(fmaf(pv.y, LOG2E, a[1]));
                const float p2 = fexp2(fmaf(pv.z, LOG2E, a[2]));
                const float p3 = fexp2(fmaf(pv.w, LOG2E, a[3]));
                lpart += (p0 + p1) + (p2 + p3);
                Pc[t4 * 2]     = (unsigned int)(unsigned short)f2bf(p0) |
                                 ((unsigned int)(unsigned short)f2bf(p1) << 16);
                Pc[t4 * 2 + 1] = (unsigned int)(unsigned short)f2bf(p2) |
                                 ((unsigned int)(unsigned short)f2bf(p3) << 16);
            }
            // ---- immediately consume this chunk's P in PV (Pc dies here) ----
            const uint4v u0 = {Pc[0], Pc[1], Pc[2], Pc[3]};
            const uint4v u1 = {Pc[4], Pc[5], Pc[6], Pc[7]};
            const short8 aP0 = __builtin_bit_cast(short8, u0);
            const short8 aP1 = __builtin_bit_cast(short8, u1);
            #pragma unroll
            for (int ks = 0; ks < 2; ++ks) {
                const short8 aP = ks ? aP1 : aP0;
                const int xr = (c * 8 + ks * 4 + quad) ^ (m15 & 7);
                const short8 bV0 = *(const short8*)&smV[(0 * 16 + m15) * 320 + xr * 8];
                const short8 bV1 = *(const short8*)&smV[(1 * 16 + m15) * 320 + xr * 8];
                const short8 bV2 = *(const short8*)&smV[(2 * 16 + m15) * 320 + xr * 8];
                const short8 bV3 = *(const short8*)&smV[(3 * 16 + m15) * 320 + xr * 8];
                O0 = __builtin_amdgcn_mfma_f32_16x16x32_bf16(aP, bV0, O0, 0, 0, 0);
                O1 = __builtin_amdgcn_mfma_f32_16x16x32_bf16(aP, bV1, O1, 0, 0, 0);
                O2 = __builtin_amdgcn_mfma_f32_16x16x32_bf16(aP, bV2, O2, 0, 0, 0);
                O3 = __builtin_amdgcn_mfma_f32_16x16x32_bf16(aP, bV3, O3, 0, 0, 0);
            }
        }

        // ---- row sum across quads (each quad holds a disjoint n-subset) ----
        float lrow = lpart;
        lrow += __shfl_xor(lrow, 16, 64);
        lrow += __shfl_xor(lrow, 32, 64);
        const float invl = 1.0f / lrow;
        float inv[4];
        #pragma unroll
        for (int r = 0; r < 4; ++r)
            inv[r] = __shfl(invl, (l & 48) | (quad * 4 + r), 64);

        // ---- normalize + direct bf16 output aoT[b][s][c] ----
        #pragma unroll
        for (int r = 0; r < 4; ++r) {
            const int s = s0 + si * 128 + w * 16 + quad * 4 + r;
            short* orow = &aoT[(size_t)(b * S + s) * 512 + h * 64 + m15];
            orow[0]  = f2bf(O0[r] * inv[r]);
            orow[16] = f2bf(O1[r] * inv[r]);
            orow[32] = f2bf(O2[r] * inv[r]);
            orow[48] = f2bf(O3[r] * inv[r]);
        }
    }
}

// ---------------------------------------------------------------------------
extern "C" void kernel_launch(void* const* d_in, const int* in_sizes, int n_in,
                              void* d_out, int out_size, void* d_ws, size_t ws_size,
                              hipStream_t stream) {
    const float* x    = (const float*)d_in[0];
    const float* Wqkv = (const float*)d_in[1];
    const float* Wout = (const float*)d_in[2];
    const float* bout = (const float*)d_in[3];
    const float* pos  = (const float*)d_in[4];
    char* ws = (char*)d_ws;
    float* xp   = (float*)(ws + 0);            // [32][512][320] f32   20971520 B
    short* xT   = (short*)(ws + 20971520);     // [32][1024][512] bf16 33554432 B
    short* xpT  = (short*)(ws + 54525952);     // [32][320][512] bf16  10485760 B
    short* qT   = (short*)(ws + 65011712);     // [32][1024][512] bf16 33554432 B
    short* kvT  = (short*)(ws + 98566144);     // [32][320][1024] bf16 20971520 B
    short* aoT  = (short*)(ws + 119537664);    // [32][1024][512] bf16 33554432 B
    short* Wbf  = (short*)(ws + 153092096);    // [1536][512] bf16      1572864 B
    short* Wobf = (short*)(ws + 154664960);    // [512][512] bf16        524288 B
    float* out  = (float*)d_out;

    castw<<<dim3(768), 256, 0, stream>>>(Wqkv, Wbf, 1536 * 512);
    castw<<<dim3(256), 256, 0, stream>>>(Wout, Wobf, 512 * 512);
    pool_kernel<<<dim3(BATCH * CH / 4), 256, 0, stream>>>(x, xp);
    tcast<<<dim3(16, 8, BATCH), 256, 0, stream>>>(x, xT, CH, S);       // -> xT [s][c]
    tcast<<<dim3(5, 8, BATCH), 256, 0, stream>>>(xp, xpT, CH, NKV);    // -> xpT [n][c]
    // qT[b][s][c] = (xT . Wq) * log2e   (exp2-softmax pre-scale)
    gemm_bf16<4, 4, 3, short><<<dim3(4, 8, BATCH), 256, 0, stream>>>(
        xT, (long)S * CH, Wbf, 0, nullptr, qT, S, CH);
    // kvT[b][n][ckv] = sigmoid(xpT . Wkv), k-cols pre-scaled 0.125
    gemm_bf16<2, 8, 1, short><<<dim3(4, 5, BATCH), 256, 0, stream>>>(
        xpT, (long)NKV * CH, Wbf + CH * CH, 0, nullptr, kvT, NKV, 2 * CH);
    attn_mfma<<<dim3(2, HEADS, BATCH), 512, 0, stream>>>(qT, kvT, pos, aoT);
    // out[b][c][s] = Wout . aoT + bout  (fp32, direct coalesced)
    gemm_bf16<4, 4, 2, float><<<dim3(8, 4, BATCH), 256, 0, stream>>>(
        Wobf, 0, aoT, (long)S * CH, bout, out, CH, S);
}

// Round 4
// 279.228 us; speedup vs baseline: 2.0861x; 1.9585x over previous
//
#include <hip/hip_runtime.h>
#include <hip/hip_bf16.h>
#include <math.h>

#define HEADS 8
#define CH    512
#define S     1024
#define NKV   320
#define DH    64
#define BATCH 32

typedef __attribute__((ext_vector_type(8))) short short8;
typedef __attribute__((ext_vector_type(4))) short short4v;
typedef __attribute__((ext_vector_type(4))) float float4v;
typedef __attribute__((ext_vector_type(4))) unsigned int uint4v;

__device__ __forceinline__ short f2bf(float f) {
    __hip_bfloat16 h = __float2bfloat16(f);
    return *reinterpret_cast<short*>(&h);
}

__device__ __forceinline__ float fexp2(float x) {
#if __has_builtin(__builtin_amdgcn_exp2f)
    return __builtin_amdgcn_exp2f(x);
#else
    return exp2f(x);
#endif
}

// async global->LDS DMA, 16B/lane. LDS base must be wave-uniform; HW adds lane*16.
#define GLOAD_LDS16(gp, lp) __builtin_amdgcn_global_load_lds( \
    (const __attribute__((address_space(1))) void*)(gp),      \
    (__attribute__((address_space(3))) void*)(lp), 16, 0, 0)

// ---------------------------------------------------------------------------
// Pool x: [B,C,32,32] -> xp [B,C,320] fp32 (mean-w | mean-h | 2x2 avg)
// ---------------------------------------------------------------------------
__global__ __launch_bounds__(256) void pool_kernel(const float* __restrict__ x,
                                                   float* __restrict__ xp) {
    __shared__ float sm[4][1024];
    const int w = threadIdx.x >> 6;
    const int l = threadIdx.x & 63;
    const int p = blockIdx.x * 4 + w;
    const float* src = x + (size_t)p * 1024;
    #pragma unroll
    for (int j = 0; j < 16; ++j) sm[w][j * 64 + l] = src[j * 64 + l];
    __syncthreads();
    float* dst = xp + (size_t)p * NKV;
    const float* pl = sm[w];
    #pragma unroll
    for (int g = 0; g < 5; ++g) {
        const int nn = g * 64 + l;
        float r;
        if (nn < 32) {
            const int h = nn; float s = 0.f;
            #pragma unroll
            for (int ww = 0; ww < 32; ++ww) s += pl[h * 32 + ww];
            r = s * (1.0f / 32.0f);
        } else if (nn < 64) {
            const int ww = nn - 32; float s = 0.f;
            #pragma unroll
            for (int h = 0; h < 32; ++h) s += pl[h * 32 + ww];
            r = s * (1.0f / 32.0f);
        } else {
            const int i = nn - 64;
            const int ph = i >> 4, pw = i & 15;
            r = 0.25f * (pl[(2 * ph) * 32 + 2 * pw]     + pl[(2 * ph) * 32 + 2 * pw + 1] +
                         pl[(2 * ph + 1) * 32 + 2 * pw] + pl[(2 * ph + 1) * 32 + 2 * pw + 1]);
        }
        dst[nn] = r;
    }
}

// ---------------------------------------------------------------------------
// Transpose-cast: in [bz][R][C] fp32 -> out [bz][C][R] bf16. grid (C/64, R/64, B)
// ---------------------------------------------------------------------------
__global__ __launch_bounds__(256) void tcast(const float* __restrict__ in,
                                             short* __restrict__ out, int R, int C) {
    __shared__ float sm[64][65];
    const int t = threadIdx.x;
    const int c0 = blockIdx.x * 64, r0 = blockIdx.y * 64;
    const float* ib = in + ((size_t)blockIdx.z * R + r0) * C + c0;
    #pragma unroll
    for (int rep = 0; rep < 4; ++rep) {
        const int r = rep * 16 + (t >> 4), c = (t & 15) * 4;
        const float4 v = *(const float4*)&ib[(size_t)r * C + c];
        sm[r][c] = v.x; sm[r][c + 1] = v.y; sm[r][c + 2] = v.z; sm[r][c + 3] = v.w;
    }
    __syncthreads();
    short* ob = out + ((size_t)blockIdx.z * C + c0) * R + r0;
    #pragma unroll
    for (int rep = 0; rep < 4; ++rep) {
        const int cr = rep * 16 + (t >> 4), rc = (t & 15) * 4;
        short4v p;
        #pragma unroll
        for (int e = 0; e < 4; ++e) p[e] = f2bf(sm[rc + e][cr]);
        *(short4v*)&ob[(size_t)cr * R + rc] = p;
    }
}

// ---------------------------------------------------------------------------
// Flat fp32 -> bf16 cast (weights). n divisible by 4.
// ---------------------------------------------------------------------------
__global__ __launch_bounds__(256) void castw(const float* __restrict__ in,
                                             short* __restrict__ out, int n) {
    const int i = (blockIdx.x * 256 + threadIdx.x) * 4;
    if (i < n) {
        const float4 v = *(const float4*)&in[i];
        short4v p = {f2bf(v.x), f2bf(v.y), f2bf(v.z), f2bf(v.w)};
        *(short4v*)&out[i] = p;
    }
}

// ---------------------------------------------------------------------------
// bf16 MFMA GEMM: Out[bz][row][col] = act( sum_k A[bz][row][k]*B[bz][col][k] )
// A [*,M,K], B [*,N,K] both K-contiguous bf16, K=512. 256 thr = 4 waves (2x2),
// wave tile (MT*16)x(NT*16), block tile BM=32*MT x BN=32*NT, BK=64.
// Staging via global_load_lds(16B) into XOR-swizzled packed LDS rows:
// physical chunk pc of row r holds logical chunk pc^(r&7) -> b128 frag reads
// are 2-way-conflict-free. ACT: 0 none(bf16), 1 sigmoid+0.125 on col<512(bf16),
// 2 +bias[row] (fp32 out), 3 *log2e (bf16, for exp2-softmax Q).
// ---------------------------------------------------------------------------
template <int MT, int NT, int ACT, typename OT>
__global__ __launch_bounds__(256) void gemm_bf16(const short* __restrict__ A, long sAb,
                                                 const short* __restrict__ B, long sBb,
                                                 const float* __restrict__ bias,
                                                 OT* __restrict__ C, int M, int N) {
    constexpr int K  = 512;
    constexpr int BM = 32 * MT, BN = 32 * NT;
    __shared__ short As[BM * 64];
    __shared__ short Bs[BN * 64];
    const int t = threadIdx.x, w = t >> 6, l = t & 63;
    const int wm = w >> 1, wn = w & 1, quad = l >> 4, m15 = l & 15;
    const int bz = blockIdx.z;
    const int n0 = blockIdx.x * BN, m0 = blockIdx.y * BM;
    const short* gA = A + (size_t)sAb * bz + (size_t)m0 * K;
    const short* gB = B + (size_t)sBb * bz + (size_t)n0 * K;
    const int lrow = l >> 3;     // row within an 8-row staging group
    const int pc   = l & 7;      // physical 16B chunk within row

    const float4v zf = {0.f, 0.f, 0.f, 0.f};
    float4v acc[MT][NT];
    #pragma unroll
    for (int i = 0; i < MT; ++i)
        #pragma unroll
        for (int j = 0; j < NT; ++j) acc[i][j] = zf;

    for (int k0 = 0; k0 < K; k0 += 64) {
        #pragma unroll
        for (int ii = w; ii < BM / 8; ii += 4) {
            const int row = ii * 8 + lrow;
            const int x = pc ^ (row & 7);
            GLOAD_LDS16(gA + (size_t)row * K + k0 + x * 8, &As[ii * 512]);
        }
        #pragma unroll
        for (int ii = w; ii < BN / 8; ii += 4) {
            const int row = ii * 8 + lrow;
            const int x = pc ^ (row & 7);
            GLOAD_LDS16(gB + (size_t)row * K + k0 + x * 8, &Bs[ii * 512]);
        }
        __syncthreads();
        #pragma unroll
        for (int ks = 0; ks < 2; ++ks) {
            const int xa = (((ks * 4 + quad) ^ (m15 & 7))) * 8;
            short8 aF[MT], bF[NT];
            #pragma unroll
            for (int i = 0; i < MT; ++i)
                aF[i] = *(const short8*)&As[((wm * MT + i) * 16 + m15) * 64 + xa];
            #pragma unroll
            for (int j = 0; j < NT; ++j)
                bF[j] = *(const short8*)&Bs[((wn * NT + j) * 16 + m15) * 64 + xa];
            #pragma unroll
            for (int i = 0; i < MT; ++i)
                #pragma unroll
                for (int j = 0; j < NT; ++j)
                    acc[i][j] = __builtin_amdgcn_mfma_f32_16x16x32_bf16(aF[i], bF[j], acc[i][j], 0, 0, 0);
        }
        __syncthreads();
    }

    OT* gC = C + (size_t)bz * M * N;
    #pragma unroll
    for (int i = 0; i < MT; ++i) {
        #pragma unroll
        for (int r = 0; r < 4; ++r) {
            const int row = m0 + (wm * MT + i) * 16 + quad * 4 + r;
            float bv = 0.f;
            if (ACT == 2) bv = bias[row];
            #pragma unroll
            for (int j = 0; j < NT; ++j) {
                const int col = n0 + (wn * NT + j) * 16 + m15;
                float v = acc[i][j][r];
                if (ACT == 1) { v = 1.0f / (1.0f + __expf(-v)); if (col < 512) v *= 0.125f; }
                if (ACT == 2) v += bv;
                if (ACT == 3) v *= 1.4426950408889634f;
                if constexpr (sizeof(OT) == 2)
                    ((short*)gC)[(size_t)row * N + col] = f2bf(v);
                else
                    ((float*)gC)[(size_t)row * N + col] = v;
            }
        }
    }
}

// ---------------------------------------------------------------------------
// MFMA attention, v5 = v4 + anti-LICM memory clobber in the si-loop.
//
// v3/v4 spill diagnosis: all smK/smV fragment reads inside the si-loop are
// loop-invariant (LDS unmodified after the single barrier), so LICM hoisted
// up to 80 b128 LDS loads (~320 VGPRs) across the backedge -> spill to
// scratch (FETCH 565 MB / WRITE 293 MB of pure scratch traffic). The
// asm memory clobber at the top of each si iteration makes LDS contents
// "unknown" across the backedge, forcing per-iteration reloads (cheap,
// conflict-free) and keeping in-body pressure at the fused-chunk ~85 regs.
//
// Structure (unchanged from v4): one block = (b, h, 512 s-rows); 8 waves x 4
// s-iterations; K/V in separate LDS buffers (40960 B each -> 2 blocks/CU);
// ONE barrier total. Fused chunk loop: per 64-col chunk, 8 QK MFMA ->
// exp2+pack 8 transient dwords -> 8 PV MFMA into persistent O[4]
// (unnormalized, inv at store). sigma-permuted K staging makes PV A-frags
// the lane's own packed P dwords (zero cross-lane P traffic). No row-max
// (logits bounded); Q pre-scaled by log2e.
// ---------------------------------------------------------------------------
__global__ __launch_bounds__(512, 4) void attn_mfma(const short* __restrict__ qT,
                                                    const short* __restrict__ kvT,
                                                    const float* __restrict__ pos,
                                                    short* __restrict__ aoT) {
    __shared__ short smK[8 * 320 * 8];   // 40960 B: K packed [dg][n][8]
    __shared__ short smV[64 * 320];      // 40960 B: V^T [d][chunk x^(d&7)][8]
    const int tid = threadIdx.x, w = tid >> 6, l = tid & 63;
    const int quad = l >> 4, m15 = l & 15;
    const int b = blockIdx.z, h = blockIdx.y, s0 = blockIdx.x * 512;
    const short* kvb = kvT + (size_t)b * NKV * 1024;
    constexpr float LOG2E = 1.4426950408889634f;

    // ---- stage K, sigma-permuted rows: n_off = 32*l5+16*l3+8*l2+4*l4+2*l1+l0
    const int nperm = (l & 35) | ((l & 12) << 1) | ((l & 16) >> 2);
    #pragma unroll
    for (int i2 = w; i2 < 40; i2 += 8) {
        const int nb = i2 % 5, dg = i2 / 5;
        GLOAD_LDS16(kvb + (size_t)(nb * 64 + nperm) * 1024 + h * 64 + dg * 8,
                    &smK[(dg * 320 + nb * 64) * 8]);
    }
    // ---- V-half global->reg->LDS scatter (overlaps the K DMA in flight) ----
    // chunk x of V^T row d stored at x^(d&7)
    #pragma unroll
    for (int it = 0; it < 5; ++it) {
        const int i2 = it * 512 + tid;
        const int n5 = i2 & 31, d8 = (i2 >> 5) & 7, nb = i2 >> 8;
        const int n = nb * 32 + n5;
        const short8 v = *(const short8*)&kvb[(size_t)n * 1024 + 512 + h * 64 + d8 * 8];
        const int x = n >> 3;
        #pragma unroll
        for (int e = 0; e < 8; ++e)
            smV[(d8 * 8 + e) * 320 + ((x ^ e) * 8) + (n & 7)] = v[e];
    }

    __syncthreads();   // the ONLY barrier: K DMA + V scatter complete

    const short* qbase = qT + (size_t)(b * S + s0 + w * 16 + m15) * 512 + h * 64;
    const float4v zf = {0.f, 0.f, 0.f, 0.f};

    #pragma unroll 1
    for (int si = 0; si < 4; ++si) {
        // Anti-LICM: LDS contents "may have changed" across the backedge, so
        // smK/smV fragment loads cannot be hoisted out of the loop (the v3/v4
        // 320-VGPR live-range -> scratch-spill failure mode).
        asm volatile("" ::: "memory");

        const short* qb = qbase + (size_t)si * 128 * 512;
        const short8 cq0 = *(const short8*)&qb[quad * 8];
        const short8 cq1 = *(const short8*)&qb[32 + quad * 8];
        const float* posrow = pos + (size_t)(s0 + si * 128 + w * 16 + m15) * NKV + quad * 8;

        float4v O0 = zf, O1 = zf, O2 = zf, O3 = zf;
        float lpart = 0.f;

        #pragma unroll
        for (int c = 0; c < 5; ++c) {
            unsigned int Pc[8];
            // ---- 4 score tiles of this 64-col chunk: QK^T + pos + exp2 + pack
            #pragma unroll
            for (int t4 = 0; t4 < 4; ++t4) {
                const int tt = c * 4 + t4;
                float4v a = zf;
                const short8 k0 = *(const short8*)&smK[(quad * 320 + tt * 16 + m15) * 8];
                const short8 k1 = *(const short8*)&smK[((4 + quad) * 320 + tt * 16 + m15) * 8];
                a = __builtin_amdgcn_mfma_f32_16x16x32_bf16(k0, cq0, a, 0, 0, 0);
                a = __builtin_amdgcn_mfma_f32_16x16x32_bf16(k1, cq1, a, 0, 0, 0);
                const int n0 = c * 64 + (t4 >> 1) * 32 + (t4 & 1) * 4;
                const float4 pv = *(const float4*)&posrow[n0];
                const float p0 = fexp2(fmaf(pv.x, LOG2E, a[0]));
                const float p1 = fexp2(fmaf(pv.y, LOG2E, a[1]));
                const float p2 = fexp2(fmaf(pv.z, LOG2E, a[2]));
                const float p3 = fexp2(fmaf(pv.w, LOG2E, a[3]));
                lpart += (p0 + p1) + (p2 + p3);
                Pc[t4 * 2]     = (unsigned int)(unsigned short)f2bf(p0) |
                                 ((unsigned int)(unsigned short)f2bf(p1) << 16);
                Pc[t4 * 2 + 1] = (unsigned int)(unsigned short)f2bf(p2) |
                                 ((unsigned int)(unsigned short)f2bf(p3) << 16);
            }
            // ---- immediately consume this chunk's P in PV (Pc dies here) ----
            const uint4v u0 = {Pc[0], Pc[1], Pc[2], Pc[3]};
            const uint4v u1 = {Pc[4], Pc[5], Pc[6], Pc[7]};
            const short8 aP0 = __builtin_bit_cast(short8, u0);
            const short8 aP1 = __builtin_bit_cast(short8, u1);
            #pragma unroll
            for (int ks = 0; ks < 2; ++ks) {
                const short8 aP = ks ? aP1 : aP0;
                const int xr = (c * 8 + ks * 4 + quad) ^ (m15 & 7);
                const short8 bV0 = *(const short8*)&smV[(0 * 16 + m15) * 320 + xr * 8];
                const short8 bV1 = *(const short8*)&smV[(1 * 16 + m15) * 320 + xr * 8];
                const short8 bV2 = *(const short8*)&smV[(2 * 16 + m15) * 320 + xr * 8];
                const short8 bV3 = *(const short8*)&smV[(3 * 16 + m15) * 320 + xr * 8];
                O0 = __builtin_amdgcn_mfma_f32_16x16x32_bf16(aP, bV0, O0, 0, 0, 0);
                O1 = __builtin_amdgcn_mfma_f32_16x16x32_bf16(aP, bV1, O1, 0, 0, 0);
                O2 = __builtin_amdgcn_mfma_f32_16x16x32_bf16(aP, bV2, O2, 0, 0, 0);
                O3 = __builtin_amdgcn_mfma_f32_16x16x32_bf16(aP, bV3, O3, 0, 0, 0);
            }
        }

        // ---- row sum across quads (each quad holds a disjoint n-subset) ----
        float lrow = lpart;
        lrow += __shfl_xor(lrow, 16, 64);
        lrow += __shfl_xor(lrow, 32, 64);
        const float invl = 1.0f / lrow;
        float inv[4];
        #pragma unroll
        for (int r = 0; r < 4; ++r)
            inv[r] = __shfl(invl, (l & 48) | (quad * 4 + r), 64);

        // ---- normalize + direct bf16 output aoT[b][s][c] ----
        #pragma unroll
        for (int r = 0; r < 4; ++r) {
            const int s = s0 + si * 128 + w * 16 + quad * 4 + r;
            short* orow = &aoT[(size_t)(b * S + s) * 512 + h * 64 + m15];
            orow[0]  = f2bf(O0[r] * inv[r]);
            orow[16] = f2bf(O1[r] * inv[r]);
            orow[32] = f2bf(O2[r] * inv[r]);
            orow[48] = f2bf(O3[r] * inv[r]);
        }
    }
}

// ---------------------------------------------------------------------------
extern "C" void kernel_launch(void* const* d_in, const int* in_sizes, int n_in,
                              void* d_out, int out_size, void* d_ws, size_t ws_size,
                              hipStream_t stream) {
    const float* x    = (const float*)d_in[0];
    const float* Wqkv = (const float*)d_in[1];
    const float* Wout = (const float*)d_in[2];
    const float* bout = (const float*)d_in[3];
    const float* pos  = (const float*)d_in[4];
    char* ws = (char*)d_ws;
    float* xp   = (float*)(ws + 0);            // [32][512][320] f32   20971520 B
    short* xT   = (short*)(ws + 20971520);     // [32][1024][512] bf16 33554432 B
    short* xpT  = (short*)(ws + 54525952);     // [32][320][512] bf16  10485760 B
    short* qT   = (short*)(ws + 65011712);     // [32][1024][512] bf16 33554432 B
    short* kvT  = (short*)(ws + 98566144);     // [32][320][1024] bf16 20971520 B
    short* aoT  = (short*)(ws + 119537664);    // [32][1024][512] bf16 33554432 B
    short* Wbf  = (short*)(ws + 153092096);    // [1536][512] bf16      1572864 B
    short* Wobf = (short*)(ws + 154664960);    // [512][512] bf16        524288 B
    float* out  = (float*)d_out;

    castw<<<dim3(768), 256, 0, stream>>>(Wqkv, Wbf, 1536 * 512);
    castw<<<dim3(256), 256, 0, stream>>>(Wout, Wobf, 512 * 512);
    pool_kernel<<<dim3(BATCH * CH / 4), 256, 0, stream>>>(x, xp);
    tcast<<<dim3(16, 8, BATCH), 256, 0, stream>>>(x, xT, CH, S);       // -> xT [s][c]
    tcast<<<dim3(5, 8, BATCH), 256, 0, stream>>>(xp, xpT, CH, NKV);    // -> xpT [n][c]
    // qT[b][s][c] = (xT . Wq) * log2e   (exp2-softmax pre-scale)
    gemm_bf16<4, 4, 3, short><<<dim3(4, 8, BATCH), 256, 0, stream>>>(
        xT, (long)S * CH, Wbf, 0, nullptr, qT, S, CH);
    // kvT[b][n][ckv] = sigmoid(xpT . Wkv), k-cols pre-scaled 0.125
    gemm_bf16<2, 8, 1, short><<<dim3(4, 5, BATCH), 256, 0, stream>>>(
        xpT, (long)NKV * CH, Wbf + CH * CH, 0, nullptr, kvT, NKV, 2 * CH);
    attn_mfma<<<dim3(2, HEADS, BATCH), 512, 0, stream>>>(qT, kvT, pos, aoT);
    // out[b][c][s] = Wout . aoT + bout  (fp32, direct coalesced)
    gemm_bf16<4, 4, 2, float><<<dim3(8, 4, BATCH), 256, 0, stream>>>(
        Wobf, 0, aoT, (long)S * CH, bout, out, CH, S);
}